// Round 7
// baseline (301.779 us; speedup 1.0000x reference)
//
#include <hip/hip_runtime.h>

#define BATCH 131072
#define UNITS 512
#define DIM   64
#define BM    128     // rows per block: 4 waves x 32 rows
#define NFRAG 4096    // full w fragment image: 8 gu * 4 t * 2 h * 64 lanes, 16B = 64 KB

typedef __attribute__((ext_vector_type(8))) short  short8;
typedef __attribute__((ext_vector_type(4))) float  floatx4;

static __device__ __forceinline__ unsigned short f32_to_bf16(float f) {
    union { float f; unsigned int u; } c; c.f = f;
    unsigned int u = c.u;
    unsigned int r = u + 0x7fffu + ((u >> 16) & 1u);   // round-nearest-even
    return (unsigned short)(r >> 16);
}

// ---- per-row sum of squares of w ----
__global__ __launch_bounds__(256) void prep_wsq_kernel(
    const float* __restrict__ w, float* __restrict__ wsq)
{
    const int u = blockIdx.x * 4 + (threadIdx.x >> 6);
    const int d = threadIdx.x & 63;
    float v = w[u * DIM + d];
    float s = v * v;
    #pragma unroll
    for (int o = 32; o > 0; o >>= 1) s += __shfl_xor(s, o);
    if (d == 0) wsq[u] = s;
}

// ---- pre-permute w into the MFMA B-fragment-linear bf16 image ----
// frag fi = (g*4 + t)*2 + h; slot = fi*64 + lane (16 B each):
// row u = g*64 + t*16 + (lane&15), k = h*32 + (lane>>4)*8 .. +8.
__global__ __launch_bounds__(256) void prep_wfrag_kernel(
    const float* __restrict__ w, uint4* __restrict__ wbf)
{
    const int tid  = blockIdx.x * 256 + threadIdx.x;
    const int lane = tid & 63;
    const int fi   = tid >> 6;
    const int h    = fi & 1;
    const int tt   = fi >> 1;
    const int u    = (tt >> 2) * 64 + (tt & 3) * 16 + (lane & 15);
    const int k0   = h * 32 + (lane >> 4) * 8;
    const float* src = w + u * DIM + k0;
    float v[8];
    *(float4*)&v[0] = *(const float4*)src;
    *(float4*)&v[4] = *(const float4*)(src + 4);
    unsigned short p[8];
    #pragma unroll
    for (int i = 0; i < 8; ++i) p[i] = f32_to_bf16(v[i]);
    wbf[tid] = *(uint4*)p;
}

// dist[b,u] = ||x_b||^2 + ||w_u||^2 - 2 * x_b . w_u
//
// OCCUPANCY CELL COMPLETION (resubmit of R6 — container died before
// measurement). Clock-normalized ledger (dist+prep us):
//   loads-in-loop  + 4 waves/SIMD : 120-129   (R0/R3)
//   no-loads       + 2 waves/SIMD : 117-122   (R4/R5; 64B vs 256B segs null)
//   no-loads       + 4 waves/SIMD : THIS KERNEL
// Pipe accounting (LDS ~23us, VALU ~12us, MFMA ~5us, traffic floor ~50us)
// leaves ~60us unexplained; the per-wave chain ds_read(lgkm)->MFMA->VALU->
// store carries ~500+ cyc latency per gu-step, exposed at 2 waves/SIMD.
// This round moves ONLY occupancy: column-half blocks shrink the LDS
// fragment image to 32 KB (+1 KB wsq) -> 4 blocks/CU at 256T = 4 waves/
// SIMD, VGPR capped at 128 via __launch_bounds__(256,4) (inner loop holds
// one t's B-frags at a time). Main loop still has ZERO vmem loads; stores
// register-direct (swapped MFMA operands), same pattern as R4.
__global__ __launch_bounds__(256, 4) void dist_kernel(
    const float* __restrict__ x,
    const uint4* __restrict__ wbf,
    const float* __restrict__ wsq,
    float* __restrict__ out)
{
    __shared__ __align__(16) uint4 wbs[2048];      // 32 KB: this block's col-half
    __shared__ __align__(16) float wsq_s[256];     // 1 KB  -> 33 KB total

    const int tid  = threadIdx.x;
    const int wave = tid >> 6;
    const int lane = tid & 63;
    const int l15  = lane & 15;
    const int quad = lane >> 4;

    const int bid  = blockIdx.x;
    const int ch   = bid >> 10;                    // column half: 0 or 1
    const int rb   = bid & 1023;                   // row block
    const int row0 = rb * BM;

    // ---- stage this half's fragment image (contiguous 32 KB of wbf) + wsq ----
    #pragma unroll
    for (int i = 0; i < 8; ++i)
        wbs[i * 256 + tid] = wbf[ch * 2048 + i * 256 + tid];
    wsq_s[tid] = wsq[ch * 256 + tid];

    // ---- preload x fragments to registers (verified swapped layout:
    //      frag row = l15, k = quad*8+j; xs2 = ||x_row(l15)||^2) ----
    short8 a[2][2];
    float  xs2[2];
    #pragma unroll
    for (int mf = 0; mf < 2; ++mf) {
        const float* xr = x + (size_t)(row0 + wave * 32 + mf * 16 + l15) * DIM;
        float v[16];
        *(float4*)&v[0]  = *(const float4*)(xr + quad * 8);
        *(float4*)&v[4]  = *(const float4*)(xr + quad * 8 + 4);
        *(float4*)&v[8]  = *(const float4*)(xr + 32 + quad * 8);
        *(float4*)&v[12] = *(const float4*)(xr + 32 + quad * 8 + 4);
        float s = 0.f;
        unsigned short p[16];
        #pragma unroll
        for (int i = 0; i < 16; ++i) { s += v[i] * v[i]; p[i] = f32_to_bf16(v[i]); }
        a[mf][0] = *(short8*)&p[0];
        a[mf][1] = *(short8*)&p[8];
        // the 4 lanes sharing l15 jointly hold all 64 elems of row l15
        s += __shfl_xor(s, 16);
        s += __shfl_xor(s, 32);
        xs2[mf] = s;
    }
    __syncthreads();                               // wbs + wsq_s ready; no vmem loads after

    const int   rowb = row0 + wave * 32;
    float*      outb = out + (size_t)ch * 256;

    for (int g = 0; g < 4; ++g) {
        #pragma unroll
        for (int t = 0; t < 4; ++t) {
            // one linear conflict-free ds_read_b128 per half-frag
            const int fb = ((g * 4 + t) * 2) * 64 + lane;
            uint4 r0 = wbs[fb];
            uint4 r1 = wbs[fb + 64];
            const short8 b0 = *(short8*)&r0;
            const short8 b1 = *(short8*)&r1;
            const floatx4 wq = *(const floatx4*)&wsq_s[g * 64 + t * 16 + quad * 4];

            #pragma unroll
            for (int mf = 0; mf < 2; ++mf) {
                floatx4 acc = floatx4{0.f, 0.f, 0.f, 0.f};
                // swapped operands -> lane(quad,l15) holds
                // D[u = colb + t*16 + quad*4 + i][row = l15]
                acc = __builtin_amdgcn_mfma_f32_16x16x32_bf16(b0, a[mf][0], acc, 0, 0, 0);
                acc = __builtin_amdgcn_mfma_f32_16x16x32_bf16(b1, a[mf][1], acc, 0, 0, 0);

                floatx4 vo;
                #pragma unroll
                for (int i = 0; i < 4; ++i)
                    vo[i] = xs2[mf] + wq[i] - 2.0f * acc[i];

                float* dst = outb + (size_t)(rowb + mf * 16 + l15) * UNITS
                                  + g * 64 + t * 16 + quad * 4;
                *(floatx4*)dst = vo;
            }
        }
    }
}

extern "C" void kernel_launch(void* const* d_in, const int* in_sizes, int n_in,
                              void* d_out, int out_size, void* d_ws, size_t ws_size,
                              hipStream_t stream) {
    const float* x = (const float*)d_in[0];
    const float* w = (const float*)d_in[1];
    float* out = (float*)d_out;

    uint4* wbf = (uint4*)d_ws;                                  // 64 KB frag image
    float* wsq = (float*)((char*)d_ws + NFRAG * sizeof(uint4)); // 2 KB

    prep_wsq_kernel<<<UNITS / 4, 256, 0, stream>>>(w, wsq);
    prep_wfrag_kernel<<<NFRAG / 256, 256, 0, stream>>>(w, wbf);
    dist_kernel<<<2 * (BATCH / BM), 256, 0, stream>>>(x, wbf, wsq, out);
}